// Round 7
// baseline (57.779 us; speedup 1.0000x reference)
//
#include <hip/hip_runtime.h>
#include <math.h>

typedef __attribute__((ext_vector_type(8))) _Float16 half8;
typedef __attribute__((ext_vector_type(4))) float f32x4;
typedef __attribute__((ext_vector_type(2))) float f32x2;

constexpr int B_   = 32768;
constexpr int NKPS = 14;
constexpr int DIM  = 42;
constexpr int H1_  = 1024;
constexpr int NDOF = 7;

__device__ __forceinline__ void gload_lds16(const _Float16* g, _Float16* l) {
    __builtin_amdgcn_global_load_lds(
        (const __attribute__((address_space(1))) void*)g,
        (__attribute__((address_space(3))) void*)l,
        16, 0, 0);
}

// ---------------------------------------------------------------------------
// K0: pack B = [W1_hi(42); W1_hi(42); W1_lo(42); b1_hi; b1_lo] (K=128 x N=1024
// f16) chunk-contiguous for LDS staging:
//   frag = (c*4+ks)*8 + w   (c = ntile>>3 chunk, w = ntile&7, ks = k/32)
//   B1f[(frag*64+lane)*8+j] = B[k=ks*32+(lane>>4)*8+j][n=(c*8+w)*16+(lane&15)]
// Chunk c occupies bytes [c*32768, (c+1)*32768). Also W2 [1024][7]->[1024][8].
// ---------------------------------------------------------------------------
__global__ __launch_bounds__(256)
void prep_kernel(const float* __restrict__ W1, const float* __restrict__ b1,
                 const float* __restrict__ W2,
                 _Float16* __restrict__ B1f, float* __restrict__ W2p)
{
    const int T = blockIdx.x * 256 + threadIdx.x;
    if (T < 16384) {
        const int lane = T & 63;
        const int frag = T >> 6;          // 0..255
        const int w    = frag & 7;
        const int ks   = (frag >> 3) & 3;
        const int c    = frag >> 5;
        const int ntile = c * 8 + w;
        const int n     = ntile * 16 + (lane & 15);
        const int kbase = ks * 32 + ((lane >> 4) << 3);
        half8 s;
#pragma unroll
        for (int j = 0; j < 8; ++j) {
            const int k = kbase + j;
            _Float16 hv;
            if (k < 42) {
                hv = (_Float16)W1[k * H1_ + n];
            } else if (k < 84) {
                hv = (_Float16)W1[(k - 42) * H1_ + n];
            } else if (k < 126) {
                const float x = W1[(k - 84) * H1_ + n];
                const _Float16 hi = (_Float16)x;
                hv = (_Float16)(x - (float)hi);
            } else if (k == 126) {
                hv = (_Float16)b1[n];
            } else {
                const float x = b1[n];
                const _Float16 hi = (_Float16)x;
                hv = (_Float16)(x - (float)hi);
            }
            s[j] = hv;
        }
        *((half8*)(B1f + (long)T * 8)) = s;
    } else if (T < 16384 + 1024) {
        const int n = T - 16384;
#pragma unroll
        for (int d = 0; d < 7; ++d) W2p[n * 8 + d] = W2[n * 7 + d];
        W2p[n * 8 + 7] = 0.f;
    }
}

// ---------------------------------------------------------------------------
// K1: MLP. 512 thr / 8 waves, M-tile 64 (mt=0..3). B1 staged chunk-by-chunk
// (8 chunks x 32 KB) via global_load_lds, double-buffered, counted vmcnt(4),
// raw s_barrier. Wave w handles ntile = c*8+w per chunk. W2 in LDS.
// Swapped-operand MFMA -> C[n][m]; hidden reduction within-lane.
// ---------------------------------------------------------------------------
__global__ __launch_bounds__(512, 2)
void mlp_kernel(const float* __restrict__ joints,
                const _Float16* __restrict__ B1f,
                const float* __restrict__ W2p,
                const float* __restrict__ b2,
                float* __restrict__ outAng)
{
    __shared__ __align__(16) _Float16 Bbuf[2][16384];   // 2 x 32 KB
    __shared__ __align__(16) float W2a[1024][4];        // 16 KB (d 0..3)
    __shared__ __align__(16) float W2b[1024][4];        // 16 KB (d 4..7)
    __shared__ __align__(16) _Float16 Alds[64][136];    // 17 KB
    __shared__ float sbuf[64][8];                       // 2 KB

    const int  tid  = threadIdx.x;
    const long bm   = (long)blockIdx.x * 64;
    const int  lane = tid & 63;
    const int  w    = tid >> 6;     // wave 0..7
    const int  g    = lane >> 4;    // 0..3
    const int  lm   = lane & 15;

    // ---- issue chunk 0 staging first (in flight during all prologue work)
#pragma unroll
    for (int r = 0; r < 4; ++r)
        gload_lds16(B1f + r * 4096 + tid * 8,
                    &Bbuf[0][0] + r * 4096 + w * 512);

    // ---- stage W2 into LDS ----
#pragma unroll
    for (int i = 0; i < 2; ++i) {
        const int n = i * 512 + tid;
        const f32x4 va = *((const f32x4*)(W2p + (long)n * 8));
        const f32x4 vb = *((const f32x4*)(W2p + (long)n * 8 + 4));
        *((f32x4*)W2a[n]) = va;
        *((f32x4*)W2b[n]) = vb;
    }

    ((float*)sbuf)[tid] = 0.f;

    // ---- stage A: x split [x_hi | x_lo | x_hi | 1 | 1] as f16 ----
    {
        const int r  = tid >> 3;      // 0..63
        const int c8 = tid & 7;
        const float* jr = joints + (bm + r) * DIM;
#pragma unroll
        for (int h2 = 0; h2 < 2; ++h2) {
            const int gi = c8 + h2 * 8;   // 0..15
            half8 s;
#pragma unroll
            for (int j = 0; j < 8; ++j) {
                const int k = gi * 8 + j;
                _Float16 hv;
                if (k < 42) {
                    hv = (_Float16)(jr[k] - jr[k % 3]);
                } else if (k < 84) {
                    const int km = k - 42;
                    const float x = jr[km] - jr[km % 3];
                    const _Float16 hi = (_Float16)x;
                    hv = (_Float16)(x - (float)hi);
                } else if (k < 126) {
                    const int km = k - 84;
                    hv = (_Float16)(jr[km] - jr[km % 3]);
                } else {
                    hv = (_Float16)1.0f;
                }
                s[j] = hv;
            }
            *((half8*)&Alds[r][gi * 8]) = s;
        }
    }
    __syncthreads();   // drains vmcnt(0): chunk 0 resident; Alds/W2 visible

    // ---- x fragments from LDS into registers ----
    half8 a[4][4];
#pragma unroll
    for (int mt = 0; mt < 4; ++mt)
#pragma unroll
        for (int ks = 0; ks < 4; ++ks)
            a[mt][ks] = *((const half8*)&Alds[mt * 16 + lm][ks * 32 + g * 8]);

    f32x2 angp[4][4];
#pragma unroll
    for (int mt = 0; mt < 4; ++mt)
#pragma unroll
        for (int p = 0; p < 4; ++p) angp[mt][p] = (f32x2){0.f, 0.f};

    // ---- main loop: 8 chunks, double-buffered staging ----
#pragma unroll
    for (int c = 0; c < 8; ++c) {
        if (c < 7) {
            const _Float16* gsrc = B1f + (long)(c + 1) * 16384 + tid * 8;
            _Float16* ldst = &Bbuf[(c + 1) & 1][0] + w * 512;
#pragma unroll
            for (int r = 0; r < 4; ++r)
                gload_lds16(gsrc + r * 4096, ldst + r * 4096);
            asm volatile("s_waitcnt vmcnt(4)" ::: "memory");
        } else {
            asm volatile("s_waitcnt vmcnt(0)" ::: "memory");
        }
        __builtin_amdgcn_s_barrier();   // chunk c resident for all waves

        const int ntile = c * 8 + w;
        half8 bfr[4];
#pragma unroll
        for (int ks = 0; ks < 4; ++ks)
            bfr[ks] = *((const half8*)&Bbuf[c & 1][((ks * 8 + w) * 64 + lane) * 8]);

        f32x4 acc[4];
#pragma unroll
        for (int mt = 0; mt < 4; ++mt) acc[mt] = (f32x4){0.f, 0.f, 0.f, 0.f};
#pragma unroll
        for (int ks = 0; ks < 4; ++ks)
#pragma unroll
            for (int mt = 0; mt < 4; ++mt)
                acc[mt] = __builtin_amdgcn_mfma_f32_16x16x32_f16(bfr[ks], a[mt][ks], acc[mt], 0, 0, 0);

        // epilogue: lane holds h[n][m], n = ntile*16+g*4+r, m = mt*16+lm
#pragma unroll
        for (int r = 0; r < 4; ++r) {
            const int n = ntile * 16 + g * 4 + r;
            const f32x4 wa = *((const f32x4*)W2a[n]);
            const f32x4 wb = *((const f32x4*)W2b[n]);
            const f32x2 w01 = (f32x2){wa[0], wa[1]};
            const f32x2 w23 = (f32x2){wa[2], wa[3]};
            const f32x2 w45 = (f32x2){wb[0], wb[1]};
            const f32x2 w67 = (f32x2){wb[2], wb[3]};
#pragma unroll
            for (int mt = 0; mt < 4; ++mt) {
                const float h = fmaxf(acc[mt][r], 0.f);
                const f32x2 hv = (f32x2){h, h};
                angp[mt][0] = __builtin_elementwise_fma(hv, w01, angp[mt][0]);
                angp[mt][1] = __builtin_elementwise_fma(hv, w23, angp[mt][1]);
                angp[mt][2] = __builtin_elementwise_fma(hv, w45, angp[mt][2]);
                angp[mt][3] = __builtin_elementwise_fma(hv, w67, angp[mt][3]);
            }
        }
        __builtin_amdgcn_s_barrier();   // all waves done with Bbuf[c&1]
    }

    // ---- reduce across the 4 lane-groups, accumulate per-row in LDS ----
    float red[4][8];
#pragma unroll
    for (int mt = 0; mt < 4; ++mt)
#pragma unroll
        for (int p = 0; p < 4; ++p) {
            red[mt][p * 2 + 0] = angp[mt][p][0];
            red[mt][p * 2 + 1] = angp[mt][p][1];
        }
#pragma unroll
    for (int mt = 0; mt < 4; ++mt)
#pragma unroll
        for (int i = 0; i < 8; ++i) {
            float v = red[mt][i];
            v += __shfl_xor(v, 16, 64);
            v += __shfl_xor(v, 32, 64);
            red[mt][i] = v;
        }
    if (lane < 16) {
#pragma unroll
        for (int mt = 0; mt < 4; ++mt)
#pragma unroll
            for (int i = 0; i < 8; ++i)
                atomicAdd(&sbuf[mt * 16 + lane][i], red[mt][i]);
    }
    __syncthreads();

    {
        const int m = tid >> 3, d = tid & 7;
        if (d < 7)
            outAng[(bm + m) * 7 + d] = sbuf[m][d] + b2[d];
    }
}

// ---------------------------------------------------------------------------
// K2: per-row FK + Kabsch (f64 Jacobi), reads angles from d_out. (proven)
// ---------------------------------------------------------------------------
#define JROT(app, aqq, apq, arp, arq, v0p, v0q, v1p, v1q, v2p, v2q) do { \
    double _apq = (apq); \
    if (fabs(_apq) > 1e-300) { \
        double _tau = ((aqq) - (app)) / (2.0 * _apq); \
        double _t = ((_tau >= 0.0) ? 1.0 : -1.0) / (fabs(_tau) + sqrt(1.0 + _tau*_tau)); \
        double _c = 1.0 / sqrt(1.0 + _t*_t); \
        double _s = _t * _c; \
        (app) -= _t * _apq; \
        (aqq) += _t * _apq; \
        (apq) = 0.0; \
        { double _rp = (arp), _rq = (arq); \
          (arp) = _c*_rp - _s*_rq; (arq) = _s*_rp + _c*_rq; } \
        { double _v = (v0p); (v0p) = _c*_v - _s*(v0q); (v0q) = _s*_v + _c*(v0q); } \
        { double _v = (v1p); (v1p) = _c*_v - _s*(v1q); (v1q) = _s*_v + _c*(v1q); } \
        { double _v = (v2p); (v2p) = _c*_v - _s*(v2q); (v2q) = _s*_v + _c*(v2q); } \
    } \
} while (0)

#define SWAP_EIG(ea, eb, va0, vb0, va1, vb1, va2, vb2) do { \
    double _tm; \
    _tm = (ea); (ea) = (eb); (eb) = _tm; \
    _tm = (va0); (va0) = (vb0); (vb0) = _tm; \
    _tm = (va1); (va1) = (vb1); (vb1) = _tm; \
    _tm = (va2); (va2) = (vb2); (vb2) = _tm; \
} while (0)

__global__ __launch_bounds__(256)
void fk_kernel(const float* __restrict__ joints,
               const float* __restrict__ ang_in,
               float* __restrict__ out)
{
    const int b = blockIdx.x * 256 + threadIdx.x;
    if (b >= B_) return;

    const float* jr = joints + (long)b * DIM;
    const float j0x = jr[0], j0y = jr[1], j0z = jr[2];
    float q[DIM];
#pragma unroll
    for (int k = 0; k < NKPS; ++k) {
        q[3*k+0] = jr[3*k+0] - j0x;
        q[3*k+1] = jr[3*k+1] - j0y;
        q[3*k+2] = jr[3*k+2] - j0z;
    }

    float ang[NDOF];
#pragma unroll
    for (int d = 0; d < NDOF; ++d) ang[d] = ang_in[(long)b * NDOF + d];

    float R00=1.f,R01=0.f,R02=0.f, R10=0.f,R11=1.f,R12=0.f, R20=0.f,R21=0.f,R22=1.f;
    float px=0.f, py=0.f, pz=0.f;
    float Hr00=0.f,Hr01=0.f,Hr02=0.f,Hr10=0.f,Hr11=0.f,Hr12=0.f,Hr20=0.f,Hr21=0.f,Hr22=0.f;
    float sPx=0.f, sPy=0.f, sPz=0.f;
    const float LL[NDOF] = {0.333f,0.316f,0.384f,0.088f,0.107f,0.103f,0.1f};

#pragma unroll
    for (int j = 0; j < NDOF; ++j) {
        float s, c;
        sincosf(ang[j], &s, &c);
        if ((j & 1) == 0) {
            float a0=R00, a1=R01; R00 = c*a0 + s*a1; R01 = c*a1 - s*a0;
            float b0=R10, b1v=R11; R10 = c*b0 + s*b1v; R11 = c*b1v - s*b0;
            float c0=R20, c1=R21; R20 = c*c0 + s*c1; R21 = c*c1 - s*c0;
        } else {
            float a0=R00, a2=R02; R00 = c*a0 - s*a2; R02 = s*a0 + c*a2;
            float b0=R10, b2v=R12; R10 = c*b0 - s*b2v; R12 = s*b0 + c*b2v;
            float c0=R20, c2=R22; R20 = c*c0 - s*c2; R22 = s*c0 + c*c2;
        }
        px = fmaf(LL[j], R02, px);
        py = fmaf(LL[j], R12, py);
        pz = fmaf(LL[j], R22, pz);
        {
            const float qx = q[6*j+0], qy = q[6*j+1], qz = q[6*j+2];
            sPx += px; sPy += py; sPz += pz;
            Hr00 = fmaf(px, qx, Hr00); Hr01 = fmaf(px, qy, Hr01); Hr02 = fmaf(px, qz, Hr02);
            Hr10 = fmaf(py, qx, Hr10); Hr11 = fmaf(py, qy, Hr11); Hr12 = fmaf(py, qz, Hr12);
            Hr20 = fmaf(pz, qx, Hr20); Hr21 = fmaf(pz, qy, Hr21); Hr22 = fmaf(pz, qz, Hr22);
        }
        {
            const float ox = fmaf(0.05f, R00, px);
            const float oy = fmaf(0.05f, R10, py);
            const float oz = fmaf(0.05f, R20, pz);
            const float qx = q[6*j+3], qy = q[6*j+4], qz = q[6*j+5];
            sPx += ox; sPy += oy; sPz += oz;
            Hr00 = fmaf(ox, qx, Hr00); Hr01 = fmaf(ox, qy, Hr01); Hr02 = fmaf(ox, qz, Hr02);
            Hr10 = fmaf(oy, qx, Hr10); Hr11 = fmaf(oy, qy, Hr11); Hr12 = fmaf(oy, qz, Hr12);
            Hr20 = fmaf(oz, qx, Hr20); Hr21 = fmaf(oz, qy, Hr21); Hr22 = fmaf(oz, qz, Hr22);
        }
    }

    float sQx = 0.f, sQy = 0.f, sQz = 0.f;
#pragma unroll
    for (int n = 0; n < NKPS; ++n) { sQx += q[3*n+0]; sQy += q[3*n+1]; sQz += q[3*n+2]; }

    const double inv14 = 1.0 / 14.0;
    const double cpx = (double)sPx * inv14, cpy = (double)sPy * inv14, cpz = (double)sPz * inv14;
    const double cqx = (double)sQx * inv14, cqy = (double)sQy * inv14, cqz = (double)sQz * inv14;

    const double h00 = (double)Hr00 - 14.0*cpx*cqx, h01 = (double)Hr01 - 14.0*cpx*cqy, h02 = (double)Hr02 - 14.0*cpx*cqz;
    const double h10 = (double)Hr10 - 14.0*cpy*cqx, h11 = (double)Hr11 - 14.0*cpy*cqy, h12 = (double)Hr12 - 14.0*cpy*cqz;
    const double h20 = (double)Hr20 - 14.0*cpz*cqx, h21 = (double)Hr21 - 14.0*cpz*cqy, h22 = (double)Hr22 - 14.0*cpz*cqz;

    double m00 = h00*h00 + h10*h10 + h20*h20;
    double m01 = h00*h01 + h10*h11 + h20*h21;
    double m02 = h00*h02 + h10*h12 + h20*h22;
    double m11 = h01*h01 + h11*h11 + h21*h21;
    double m12 = h01*h02 + h11*h12 + h21*h22;
    double m22 = h02*h02 + h12*h12 + h22*h22;

    double v00=1.0, v01=0.0, v02=0.0;
    double v10=0.0, v11=1.0, v12=0.0;
    double v20=0.0, v21=0.0, v22=1.0;

#pragma unroll
    for (int sw = 0; sw < 5; ++sw) {
        JROT(m00, m11, m01, m02, m12, v00, v01, v10, v11, v20, v21);
        JROT(m00, m22, m02, m01, m12, v00, v02, v10, v12, v20, v22);
        JROT(m11, m22, m12, m01, m02, v01, v02, v11, v12, v21, v22);
    }

    double e0 = m00, e1 = m11, e2 = m22;
    if (e0 < e1) SWAP_EIG(e0, e1, v00, v01, v10, v11, v20, v21);
    if (e0 < e2) SWAP_EIG(e0, e2, v00, v02, v10, v12, v20, v22);
    if (e1 < e2) SWAP_EIG(e1, e2, v01, v02, v11, v12, v21, v22);

    const double s0 = sqrt(fmax(e0, 0.0));
    const double s1 = sqrt(fmax(e1, 0.0));
    const double s2 = sqrt(fmax(e2, 0.0));

    const double det = h00*(h11*h22 - h12*h21) - h01*(h10*h22 - h12*h20) + h02*(h10*h21 - h11*h20);
    const double dsg = (det >= 0.0) ? 1.0 : -1.0;

    const double tiny = 1e-30;
    const double g0 = 1.0 / fmax(s0, tiny);
    const double g1 = 1.0 / fmax(s1, tiny);
    const double g2 = dsg / fmax(s2, tiny);

    const double K00 = g0*v00*v00 + g1*v01*v01 + g2*v02*v02;
    const double K01 = g0*v00*v10 + g1*v01*v11 + g2*v02*v12;
    const double K02 = g0*v00*v20 + g1*v01*v21 + g2*v02*v22;
    const double K11 = g0*v10*v10 + g1*v11*v11 + g2*v12*v12;
    const double K12 = g0*v10*v20 + g1*v11*v21 + g2*v12*v22;
    const double K22 = g0*v20*v20 + g1*v21*v21 + g2*v22*v22;

    const double r00 = K00*h00 + K01*h01 + K02*h02;
    const double r01 = K00*h10 + K01*h11 + K02*h12;
    const double r02 = K00*h20 + K01*h21 + K02*h22;
    const double r10 = K01*h00 + K11*h01 + K12*h02;
    const double r11 = K01*h10 + K11*h11 + K12*h12;
    const double r12 = K01*h20 + K11*h21 + K12*h22;
    const double r20 = K02*h00 + K12*h01 + K22*h02;
    const double r21 = K02*h10 + K12*h11 + K22*h12;
    const double r22 = K02*h20 + K12*h21 + K22*h22;

    const double tx = cqx - (r00*cpx + r01*cpy + r02*cpz) + (double)j0x;
    const double ty = cqy - (r10*cpx + r11*cpy + r12*cpz) + (double)j0y;
    const double tz = cqz - (r20*cpx + r21*cpy + r22*cpz) + (double)j0z;

    float* po = out + (long)B_ * NDOF + (long)b * 16;
    po[0]  = (float)r00; po[1]  = (float)r01; po[2]  = (float)r02; po[3]  = (float)tx;
    po[4]  = (float)r10; po[5]  = (float)r11; po[6]  = (float)r12; po[7]  = (float)ty;
    po[8]  = (float)r20; po[9]  = (float)r21; po[10] = (float)r22; po[11] = (float)tz;
    po[12] = 0.f; po[13] = 0.f; po[14] = 0.f; po[15] = 1.f;
}

extern "C" void kernel_launch(void* const* d_in, const int* in_sizes, int n_in,
                              void* d_out, int out_size, void* d_ws, size_t ws_size,
                              hipStream_t stream) {
    const float* joints = (const float*)d_in[0];
    const float* W1     = (const float*)d_in[1];
    const float* b1     = (const float*)d_in[2];
    const float* W2     = (const float*)d_in[3];
    const float* b2     = (const float*)d_in[4];
    float* out = (float*)d_out;

    _Float16* B1f = (_Float16*)d_ws;                          // 256 KB
    float*    W2p = (float*)((char*)d_ws + 262144);           // 32 KB

    hipLaunchKernelGGL(prep_kernel, dim3(68), dim3(256), 0, stream,
                       W1, b1, W2, B1f, W2p);

    hipLaunchKernelGGL(mlp_kernel, dim3(B_ / 64), dim3(512), 0, stream,
                       joints, B1f, W2p, b2, out);

    hipLaunchKernelGGL(fk_kernel, dim3(B_ / 256), dim3(256), 0, stream,
                       joints, out, out);
}